// Round 2
// baseline (335.364 us; speedup 1.0000x reference)
//
#include <hip/hip_runtime.h>
#include <math.h>

#define S 128
#define KA 25
#define KL 25
#define PATCH (KA * KA)        // 625
#define FEAT (2 * PATCH)       // 1250  (C * KA * KA)
#define PI_F 3.14159265358979323846f

// ---------------------------------------------------------------------------
// Kernel 1: tiles + raw_aff.
// One block (256 threads) per output position l. AFF envelope built in LDS
// (its max is exactly 1 at the center, so no normalization needed).
// tiles[l,f] = x[c, li+ki, lj+kj] * ae[ki,kj];  raw_aff[l] = tiles[l,:].relu(rfs[l,:])
// float2 vectorized: row byte stride = 1250*4 = 5000 B, 8B-aligned for all l.
// ---------------------------------------------------------------------------
__global__ __launch_bounds__(256) void k_tiles_aff(const float* __restrict__ x,
                                                   const float* __restrict__ rfs,
                                                   float* __restrict__ raw_aff,
                                                   float* __restrict__ tiles) {
    __shared__ float s_ae[PATCH];
    __shared__ float s_part[4];
    const int tid = threadIdx.x;

    for (int i = tid; i < PATCH; i += 256) {
        float di = (float)(i / KA) - 12.0f;
        float dj = (float)(i % KA) - 12.0f;
        float d = sqrtf(di * di + dj * dj);
        float v = 0.0f;
        if (d < 12.5f) {
            float c = cosf(d * (PI_F / 25.0f));
            v = c * c;
        }
        s_ae[i] = v;
    }
    __syncthreads();

    const int l = blockIdx.x;
    const int li = l >> 7;
    const int lj = l & 127;
    const long base = (long)l * FEAT;
    const float2* __restrict__ rfs2 = (const float2*)(rfs + base);
    float2* __restrict__ tiles2 = (float2*)(tiles + base);

    float acc = 0.0f;
    // 625 float2 elements, 256 threads -> 3 strided iterations
    for (int f2 = tid; f2 < FEAT / 2; f2 += 256) {
        float2 rv = rfs2[f2];
        int f0 = 2 * f2;
        float t[2];
#pragma unroll
        for (int e = 0; e < 2; ++e) {
            int f = f0 + e;
            int c = (f >= PATCH) ? 1 : 0;
            int r = f - c * PATCH;
            int ki = r / KA;
            int kj = r - ki * KA;
            float xv = x[c * (152 * 152) + (li + ki) * 152 + (lj + kj)];
            t[e] = xv * s_ae[r];
        }
        tiles2[f2] = make_float2(t[0], t[1]);
        acc += t[0] * fmaxf(rv.x, 0.0f) + t[1] * fmaxf(rv.y, 0.0f);
    }

    // wave shuffle reduce + 4-slot LDS
    for (int off = 32; off > 0; off >>= 1) acc += __shfl_down(acc, off);
    if ((tid & 63) == 0) s_part[tid >> 6] = acc;
    __syncthreads();
    if (tid == 0) raw_aff[l] = s_part[0] + s_part[1] + s_part[2] + s_part[3];
}

// ---------------------------------------------------------------------------
// LRI envelope into LDS (625 floats), normalized by its max (block-wide
// max-reduce).  Called at the top of kernels 2 and 3.
// ---------------------------------------------------------------------------
__device__ void build_lri_env(float* s_le, float* s_red) {
    const int tid = threadIdx.x;
    float m = 0.0f;
    for (int i = tid; i < PATCH; i += 256) {
        float di = (float)(i / KL) - 12.0f;
        float dj = (float)(i % KL) - 12.0f;
        float d = sqrtf(di * di + dj * dj);
        float v = 0.0f;
        if (d < 12.5f) {
            float c1 = cosf(d * (PI_F / 25.0f));
            float inh = 0.0f;
            if (d < 4.5f) {
                float c2 = cosf(d * (PI_F / 9.0f));
                inh = c2 * c2;
            }
            v = c1 * c1 * (1.0f - inh);
        }
        s_le[i] = v;
        m = fmaxf(m, v);
    }
    s_red[tid] = m;
    __syncthreads();
    for (int s = 128; s > 0; s >>= 1) {
        if (tid < s) s_red[tid] = fmaxf(s_red[tid], s_red[tid + s]);
        __syncthreads();
    }
    float inv = 1.0f / s_red[0];
    __syncthreads();
    for (int i = tid; i < PATCH; i += 256) s_le[i] *= inv;
    __syncthreads();
}

// ---------------------------------------------------------------------------
// Kernel 2: final lat.  One wave (64 lanes) per position, 4 positions/block.
// lat0[n] = relu(raw_aff[n] - ada[n])  (recomputed per neighbor; raw_aff/ada
// are 64 KB each, L1/L2-resident).  lat_neg[l] = sum_f pad0(lat0)[nbr(l,f)]
// * le[f] * relu(lw[l,f]).  latf[l] = tanh(relu(lat0[l] - lat_neg + aff[l])).
// Also zeroes the scalar correlation slot for kernel 3.
// ---------------------------------------------------------------------------
__global__ __launch_bounds__(256) void k_lat(const float* __restrict__ raw_aff,
                                             const float* __restrict__ ada,
                                             const float* __restrict__ lw,
                                             float* __restrict__ latf,
                                             float* __restrict__ corr) {
    __shared__ float s_le[PATCH];
    __shared__ float s_red[256];
    build_lri_env(s_le, s_red);

    const int tid = threadIdx.x;
    const int lane = tid & 63;
    const int wv = tid >> 6;
    const int l = blockIdx.x * 4 + wv;
    const int li = l >> 7;
    const int lj = l & 127;
    const long base = (long)l * PATCH;

    const float aff_l = raw_aff[l] - ada[l];

    float acc = 0.0f;
    for (int f = lane; f < PATCH; f += 64) {
        int ki = f / KL;
        int kj = f - ki * KL;
        int ri = li + ki - 12;
        int rj = lj + kj - 12;
        float lv = 0.0f;
        if (ri >= 0 && ri < S && rj >= 0 && rj < S) {
            int n = ri * S + rj;
            lv = fmaxf(raw_aff[n] - ada[n], 0.0f);
        }
        acc += lv * s_le[f] * fmaxf(lw[base + f], 0.0f);
    }
    for (int off = 32; off > 0; off >>= 1) acc += __shfl_down(acc, off);

    if (lane == 0) {
        float lat0 = fmaxf(aff_l, 0.0f);
        float v = (lat0 - acc) /* *STRENGTH=1 */ + aff_l;
        latf[l] = tanhf(fmaxf(v, 0.0f));
    }
    if (blockIdx.x == 0 && tid == 0) corr[0] = 0.0f;
}

// ---------------------------------------------------------------------------
// Kernel 3: lat_correlations = sum_l latf[l] * sum_f padH(latf)[nbr(l,f)]
// * le[f] * relu(lw[l,f]),  pad constant = HOMEO_TARGET = 0.04.
// 128 blocks x 4 waves; each wave grid-strides over 32 positions, block
// partial -> ONE atomicAdd per block (128 total vs 4096 before: same-address
// atomic serialization at ~15 ns each was the 62 us tail).
// ---------------------------------------------------------------------------
#define CORR_BLOCKS 128
__global__ __launch_bounds__(256) void k_corr(const float* __restrict__ latf,
                                              const float* __restrict__ lw,
                                              float* __restrict__ corr) {
    __shared__ float s_le[PATCH];
    __shared__ float s_red[256];
    build_lri_env(s_le, s_red);

    const int tid = threadIdx.x;
    const int lane = tid & 63;
    const int wv = tid >> 6;
    const int gw = blockIdx.x * 4 + wv;   // global wave id, 0..511

    float wacc = 0.0f;
    for (int l = gw; l < S * S; l += CORR_BLOCKS * 4) {
        const int li = l >> 7;
        const int lj = l & 127;
        const long base = (long)l * PATCH;

        float acc = 0.0f;
        for (int f = lane; f < PATCH; f += 64) {
            int ki = f / KL;
            int kj = f - ki * KL;
            int ri = li + ki - 12;
            int rj = lj + kj - 12;
            float lv = 0.04f;  // HOMEO_TARGET padding
            if (ri >= 0 && ri < S && rj >= 0 && rj < S) lv = latf[ri * S + rj];
            acc += lv * s_le[f] * fmaxf(lw[base + f], 0.0f);
        }
        for (int off = 32; off > 0; off >>= 1) acc += __shfl_down(acc, off);
        if (lane == 0) wacc += acc * latf[l];
    }

    __syncthreads();           // s_red reuse after build_lri_env
    if (lane == 0) s_red[wv] = wacc;
    __syncthreads();
    if (tid == 0)
        atomicAdd(corr, s_red[0] + s_red[1] + s_red[2] + s_red[3]);
}

// ---------------------------------------------------------------------------
// d_out layout (flat, return order):
//   [0, 16384)              raw_aff   [1,1,128,128]
//   [16384, 32768)          lat       [1,1,128,128]
//   [32768]                 lat_correlations (scalar)
//   [32769, 32769+20480000) tiles     [16384, 1, 1250]
// ---------------------------------------------------------------------------
extern "C" void kernel_launch(void* const* d_in, const int* in_sizes, int n_in,
                              void* d_out, int out_size, void* d_ws, size_t ws_size,
                              hipStream_t stream) {
    const float* x   = (const float*)d_in[0];   // [1,2,152,152]
    const float* rfs = (const float*)d_in[1];   // [16384,1250,1]
    const float* lw  = (const float*)d_in[2];   // [16384,625,1]
    const float* ada = (const float*)d_in[3];   // [1,1,128,128]

    float* out      = (float*)d_out;
    float* raw_aff  = out;
    float* latf     = out + S * S;
    float* corr     = out + 2 * S * S;
    float* tiles    = out + 2 * S * S + 1;

    k_tiles_aff<<<S * S, 256, 0, stream>>>(x, rfs, raw_aff, tiles);
    k_lat<<<(S * S) / 4, 256, 0, stream>>>(raw_aff, ada, lw, latf, corr);
    k_corr<<<CORR_BLOCKS, 256, 0, stream>>>(latf, lw, corr);
}

// Round 3
// 229.104 us; speedup vs baseline: 1.4638x; 1.4638x over previous
//
#include <hip/hip_runtime.h>
#include <math.h>

#define S 128
#define KA 25
#define KL 25
#define PATCH (KA * KA)        // 625
#define FEAT (2 * PATCH)       // 1250  (C * KA * KA)
#define PI_F 3.14159265358979323846f

// d_ws layout (floats):
//   [0, 625)            normalized LRI_ENV
//   [640, 640+16384)    lat0 = relu(raw_aff - ada)
//   [17024, 17024+4096) per-block corr partials
#define WS_ENV 0
#define WS_LAT0 640
#define WS_PART 17024

// ---------------------------------------------------------------------------
// Kernel 1: tiles + raw_aff (+ lat0, + LRI env by block 0).
// One block (256 threads) per position l.  Scalar stride-256 loads/stores:
// tiles base byte offset is 4 mod 8 (out + 32769 floats), so float2 stores
// were misaligned-split; scalar dwords are perfectly coalesced (256B/instr).
// ---------------------------------------------------------------------------
__global__ __launch_bounds__(256) void k_tiles_aff(const float* __restrict__ x,
                                                   const float* __restrict__ rfs,
                                                   const float* __restrict__ ada,
                                                   float* __restrict__ raw_aff,
                                                   float* __restrict__ tiles,
                                                   float* __restrict__ ws) {
    __shared__ float s_ae[PATCH];
    __shared__ float s_part[4];
    const int tid = threadIdx.x;
    const int lane = tid & 63;
    const int wv = tid >> 6;

    for (int i = tid; i < PATCH; i += 256) {
        float di = (float)(i / KA) - 12.0f;
        float dj = (float)(i % KA) - 12.0f;
        float d = sqrtf(di * di + dj * dj);
        float v = 0.0f;
        if (d < 12.5f) {
            float c = cosf(d * (PI_F / 25.0f));
            v = c * c;   // AFF env max is exactly 1 at center
        }
        s_ae[i] = v;
    }
    __syncthreads();

    const int l = blockIdx.x;
    const int li = l >> 7;
    const int lj = l & 127;
    const long base = (long)l * FEAT;

    float acc = 0.0f;
    for (int f = tid; f < FEAT; f += 256) {
        int c = (f >= PATCH) ? 1 : 0;
        int r = f - c * PATCH;
        int ki = r / KA;
        int kj = r - ki * KA;
        float xv = x[c * (152 * 152) + (li + ki) * 152 + (lj + kj)];
        float t = xv * s_ae[r];
        tiles[base + f] = t;
        acc += t * fmaxf(rfs[base + f], 0.0f);   // relu(rfs)
    }

    for (int off = 32; off > 0; off >>= 1) acc += __shfl_down(acc, off);
    if (lane == 0) s_part[wv] = acc;
    __syncthreads();
    if (tid == 0) {
        float ra = s_part[0] + s_part[1] + s_part[2] + s_part[3];
        raw_aff[l] = ra;
        ws[WS_LAT0 + l] = fmaxf(ra - ada[l], 0.0f);   // lat0 for k_lat's gather
    }

    // Block 0 additionally builds the normalized LRI envelope into ws.
    if (blockIdx.x == 0) {
        __syncthreads();   // s_ae reuse
        float m = 0.0f;
        for (int i = tid; i < PATCH; i += 256) {
            float di = (float)(i / KL) - 12.0f;
            float dj = (float)(i % KL) - 12.0f;
            float d = sqrtf(di * di + dj * dj);
            float v = 0.0f;
            if (d < 12.5f) {
                float c1 = cosf(d * (PI_F / 25.0f));
                float inh = 0.0f;
                if (d < 4.5f) {
                    float c2 = cosf(d * (PI_F / 9.0f));
                    inh = c2 * c2;
                }
                v = c1 * c1 * (1.0f - inh);
            }
            s_ae[i] = v;
            m = fmaxf(m, v);
        }
        for (int off = 32; off > 0; off >>= 1) m = fmaxf(m, __shfl_down(m, off));
        if (lane == 0) s_part[wv] = m;
        __syncthreads();
        float inv = 1.0f / fmaxf(fmaxf(s_part[0], s_part[1]),
                                 fmaxf(s_part[2], s_part[3]));
        for (int i = tid; i < PATCH; i += 256) ws[WS_ENV + i] = s_ae[i] * inv;
    }
}

// ---------------------------------------------------------------------------
// Kernel 2: final lat.  One wave per position, 4 per block (4096 blocks).
// lat_neg[l] = sum_f pad0(lat0)[nbr(l,f)] * le[f] * relu(lw[l,f])
// latf[l] = tanh(relu(lat0[l] - lat_neg + aff[l]))
// ---------------------------------------------------------------------------
__global__ __launch_bounds__(256) void k_lat(const float* __restrict__ raw_aff,
                                             const float* __restrict__ ada,
                                             const float* __restrict__ lw,
                                             float* __restrict__ latf,
                                             const float* __restrict__ ws) {
    __shared__ float s_le[PATCH];
    const int tid = threadIdx.x;
    for (int i = tid; i < PATCH; i += 256) s_le[i] = ws[WS_ENV + i];
    __syncthreads();

    const int lane = tid & 63;
    const int wv = tid >> 6;
    const int l = blockIdx.x * 4 + wv;
    const int li = l >> 7;
    const int lj = l & 127;
    const long base = (long)l * PATCH;
    const float* __restrict__ lat0 = ws + WS_LAT0;

    float acc = 0.0f;
    for (int f = lane; f < PATCH; f += 64) {
        int ki = f / KL;
        int kj = f - ki * KL;
        int ri = li + ki - 12;
        int rj = lj + kj - 12;
        float lv = 0.0f;
        if (ri >= 0 && ri < S && rj >= 0 && rj < S) lv = lat0[ri * S + rj];
        acc += lv * s_le[f] * fmaxf(lw[base + f], 0.0f);
    }
    for (int off = 32; off > 0; off >>= 1) acc += __shfl_down(acc, off);

    if (lane == 0) {
        float aff_l = raw_aff[l] - ada[l];
        float lat0_l = fmaxf(aff_l, 0.0f);
        float v = (lat0_l - acc) /* *STRENGTH=1 */ + aff_l;
        latf[l] = tanhf(fmaxf(v, 0.0f));
    }
}

// ---------------------------------------------------------------------------
// Kernel 3: per-block corr partials (no atomics, full parallelism).
// partial[b] = sum_{waves in b} latf[l] * sum_f padH(latf)[nbr] * le[f] * relu(lw)
// ---------------------------------------------------------------------------
__global__ __launch_bounds__(256) void k_corr(const float* __restrict__ latf,
                                              const float* __restrict__ lw,
                                              float* __restrict__ ws) {
    __shared__ float s_le[PATCH];
    __shared__ float s_part[4];
    const int tid = threadIdx.x;
    for (int i = tid; i < PATCH; i += 256) s_le[i] = ws[WS_ENV + i];
    __syncthreads();

    const int lane = tid & 63;
    const int wv = tid >> 6;
    const int l = blockIdx.x * 4 + wv;
    const int li = l >> 7;
    const int lj = l & 127;
    const long base = (long)l * PATCH;

    float acc = 0.0f;
    for (int f = lane; f < PATCH; f += 64) {
        int ki = f / KL;
        int kj = f - ki * KL;
        int ri = li + ki - 12;
        int rj = lj + kj - 12;
        float lv = 0.04f;  // HOMEO_TARGET padding
        if (ri >= 0 && ri < S && rj >= 0 && rj < S) lv = latf[ri * S + rj];
        acc += lv * s_le[f] * fmaxf(lw[base + f], 0.0f);
    }
    for (int off = 32; off > 0; off >>= 1) acc += __shfl_down(acc, off);

    if (lane == 0) s_part[wv] = acc * latf[l];
    __syncthreads();
    if (tid == 0)
        ws[WS_PART + blockIdx.x] = s_part[0] + s_part[1] + s_part[2] + s_part[3];
}

// ---------------------------------------------------------------------------
// Kernel 4: deterministic sum of 4096 partials -> corr scalar.
// ---------------------------------------------------------------------------
__global__ __launch_bounds__(256) void k_reduce(const float* __restrict__ ws,
                                                float* __restrict__ corr) {
    __shared__ float s_part[4];
    const int tid = threadIdx.x;
    const int lane = tid & 63;
    const int wv = tid >> 6;
    float acc = 0.0f;
    for (int i = tid; i < 4096; i += 256) acc += ws[WS_PART + i];
    for (int off = 32; off > 0; off >>= 1) acc += __shfl_down(acc, off);
    if (lane == 0) s_part[wv] = acc;
    __syncthreads();
    if (tid == 0) corr[0] = s_part[0] + s_part[1] + s_part[2] + s_part[3];
}

// ---------------------------------------------------------------------------
// d_out layout (flat, return order):
//   [0, 16384)              raw_aff   [1,1,128,128]
//   [16384, 32768)          lat       [1,1,128,128]
//   [32768]                 lat_correlations (scalar)
//   [32769, 32769+20480000) tiles     [16384, 1, 1250]
// ---------------------------------------------------------------------------
extern "C" void kernel_launch(void* const* d_in, const int* in_sizes, int n_in,
                              void* d_out, int out_size, void* d_ws, size_t ws_size,
                              hipStream_t stream) {
    const float* x   = (const float*)d_in[0];   // [1,2,152,152]
    const float* rfs = (const float*)d_in[1];   // [16384,1250,1]
    const float* lw  = (const float*)d_in[2];   // [16384,625,1]
    const float* ada = (const float*)d_in[3];   // [1,1,128,128]

    float* out      = (float*)d_out;
    float* raw_aff  = out;
    float* latf     = out + S * S;
    float* corr     = out + 2 * S * S;
    float* tiles    = out + 2 * S * S + 1;
    float* ws       = (float*)d_ws;

    k_tiles_aff<<<S * S, 256, 0, stream>>>(x, rfs, ada, raw_aff, tiles, ws);
    k_lat<<<(S * S) / 4, 256, 0, stream>>>(raw_aff, ada, lw, latf, ws);
    k_corr<<<(S * S) / 4, 256, 0, stream>>>(latf, lw, ws);
    k_reduce<<<1, 256, 0, stream>>>(ws, corr);
}